// Round 2
// baseline (366.068 us; speedup 1.0000x reference)
//
#include <hip/hip_runtime.h>
#include <cstdint>

#define VOCAB_N 50000
#define EMB_N   16
#define HID_N   32
#define B_N     4096
#define T_N     500
#define TPAD    512   // padded token row length (cols 500..511 zeroed)

__device__ __forceinline__ float frcp(float x) { return __builtin_amdgcn_rcpf(x); }

// ---------------------------------------------------------------------------
// proj2[v][l] = { z_pre[l], z_pre[64+l] },  z_pre = bias + emb[v] . W
// lane l<32 gets (i-col l, g-col l); lane l>=32 gets (f-col l-32, o-col l-32)
// ---------------------------------------------------------------------------
__global__ void build_proj2_kernel(const float* __restrict__ emb,
                                   const float* __restrict__ W,
                                   const float* __restrict__ bias,
                                   float2* __restrict__ proj2) {
  __shared__ float Wl[EMB_N * 128];
  __shared__ float bl[128];
  const int tid = threadIdx.x;
  for (int i = tid; i < EMB_N * 128 / 4; i += 256)
    reinterpret_cast<float4*>(Wl)[i] = reinterpret_cast<const float4*>(W)[i];
  if (tid < 32)
    reinterpret_cast<float4*>(bl)[tid] = reinterpret_cast<const float4*>(bias)[tid];
  __syncthreads();

  const int gid = blockIdx.x * 256 + tid;
  const int v = gid >> 6;
  const int l = gid & 63;
  if (v >= VOCAB_N) return;

  const float4* ev = reinterpret_cast<const float4*>(emb + (size_t)v * EMB_N);
  float4 e0 = ev[0], e1 = ev[1], e2 = ev[2], e3 = ev[3];
  const float em[16] = {e0.x,e0.y,e0.z,e0.w, e1.x,e1.y,e1.z,e1.w,
                        e2.x,e2.y,e2.z,e2.w, e3.x,e3.y,e3.z,e3.w};
  float a0 = bl[l], a1 = bl[64 + l];
#pragma unroll
  for (int e = 0; e < EMB_N; ++e) {
    a0 = fmaf(em[e], Wl[e * 128 + l],      a0);
    a1 = fmaf(em[e], Wl[e * 128 + 64 + l], a1);
  }
  proj2[(size_t)v * 64 + l] = make_float2(a0, a1);
}

// ---------------------------------------------------------------------------
// Scan: 1 row per wave, 64 lanes. Lane l owns z-cols {l, 64+l}.
// Weights in VGPRs (64/lane), h broadcast vector in VGPRs (32/lane) refreshed
// per step via a 1-write + 8x ds_read_b128 LDS round-trip.
// ---------------------------------------------------------------------------
__global__ __launch_bounds__(256, 4)
void lstm_scan2_kernel(const int*    __restrict__ tokens,
                       const float*  __restrict__ rec_kernel,  // [32][128]
                       const float2* __restrict__ proj2,       // [VOCAB][64]
                       float*        __restrict__ out) {
  __shared__ int   tokl[4][TPAD];    // 8 KiB
  __shared__ float hbuf[4][HID_N];   // 512 B

  const int tid  = threadIdx.x;
  const int wrow = tid >> 6;                 // wave in block = row in block
  const int lane = tid & 63;
  const int l    = lane;
  const int row  = blockIdx.x * 4 + wrow;

  // ---- stage tokens: 4 rows x 500 ints, contiguous in global ----
  {
    const int4* src = reinterpret_cast<const int4*>(tokens + (size_t)blockIdx.x * 4 * T_N);
    for (int i = tid; i < 4 * T_N / 4; i += 256) {
      int4 v4 = src[i];
      int g = 4 * i;
      int r = g / T_N;                // 500 % 4 == 0 -> int4 never straddles rows
      int cidx = g - r * T_N;
      *reinterpret_cast<int4*>(&tokl[r][cidx]) = v4;
    }
    if (tid < 48) {                   // zero pad cols 500..511
      int r = tid / 12, cc = T_N + (tid % 12);
      tokl[r][cc] = 0;
    }
  }

  // ---- recurrent weights: wr0[k] = R[k][l], wr1[k] = R[k][64+l] ----
  float wr0[HID_N], wr1[HID_N];
#pragma unroll
  for (int k = 0; k < HID_N; ++k) {
    wr0[k] = rec_kernel[k * 128 + l];
    wr1[k] = rec_kernel[k * 128 + 64 + l];
  }

  // per-lane activation constants for zB (low lanes: tanh, high lanes: sigmoid)
  const bool lo = (lane < 32);
  const float sB = lo ?  2.8853900817779268f : -1.4426950408889634f;
  const float mB = lo ? -2.0f : 1.0f;
  const float aB = lo ?  1.0f : 0.0f;

  __syncthreads();

  float c = 0.0f, h = 0.0f;
  float4 h4[8];
#pragma unroll
  for (int q = 0; q < 8; ++q) h4[q] = make_float4(0.f, 0.f, 0.f, 0.f);

  float* hrow = &hbuf[wrow][0];
  const int kidx = lane & 31;

  // ---- prologue: token groups 0..3 and 4..7 as wave-uniform scalars ----
  int4 g0v = *reinterpret_cast<const int4*>(&tokl[wrow][0]);
  int4 g1v = *reinterpret_cast<const int4*>(&tokl[wrow][4]);
  int tg0 = __builtin_amdgcn_readfirstlane(g0v.x);
  int tg1 = __builtin_amdgcn_readfirstlane(g0v.y);
  int tg2 = __builtin_amdgcn_readfirstlane(g0v.z);
  int tg3 = __builtin_amdgcn_readfirstlane(g0v.w);
  int tn0 = __builtin_amdgcn_readfirstlane(g1v.x);
  int tn1 = __builtin_amdgcn_readfirstlane(g1v.y);
  int tn2 = __builtin_amdgcn_readfirstlane(g1v.z);
  int tn3 = __builtin_amdgcn_readfirstlane(g1v.w);

  float2 p0 = proj2[(size_t)tg0 * 64 + l];   // step 0
  float2 p1 = proj2[(size_t)tg1 * 64 + l];   // step 1

  auto step = [&](int stok, int ptok, float2& pcur) {
    const float xA = pcur.x, xB = pcur.y;

    // issue prefetch for t+2 into the same slot (consumed two phases later)
    pcur = proj2[(size_t)ptok * 64 + l];

    // recurrent matvec: 64 FMAs, 4 accumulator chains
    float a0 = xA, a1 = xB, b0 = 0.f, b1 = 0.f;
#pragma unroll
    for (int q = 0; q < 8; ++q) {
      const float4 hq = h4[q];
      a0 = fmaf(hq.x, wr0[4*q+0], a0); a1 = fmaf(hq.x, wr1[4*q+0], a1);
      b0 = fmaf(hq.y, wr0[4*q+1], b0); b1 = fmaf(hq.y, wr1[4*q+1], b1);
      a0 = fmaf(hq.z, wr0[4*q+2], a0); a1 = fmaf(hq.z, wr1[4*q+2], a1);
      b0 = fmaf(hq.w, wr0[4*q+3], b0); b1 = fmaf(hq.w, wr1[4*q+3], b1);
    }
    const float zA = a0 + b0;
    const float zB = a1 + b1;

    if (stok != 0) {                       // wave-uniform branch
      // zA: always sigmoid -> P = i (lo) / f (hi)
      float eA = exp2f(zA * -1.4426950408889634f);
      float P  = frcp(1.0f + eA);
      // zB: tanh (lo) / sigmoid (hi) via per-lane constants -> Q = g / o
      float eB = exp2f(zB * sB);
      float rB = frcp(1.0f + eB);
      float Q  = fmaf(mB, rB, aB);

      // cross-half exchange
      float P2 = __shfl_xor(P, 32);
      float Q2 = __shfl_xor(Q, 32);
      float gi = lo ? P  : P2;
      float gf = lo ? P2 : P;
      float gg = lo ? Q  : Q2;
      float go = lo ? Q2 : Q;

      float cn = fmaf(gf, c, gi * gg);
      float eC = exp2f(cn * 2.8853900817779268f);
      float tc = fmaf(-2.0f, frcp(1.0f + eC), 1.0f);
      float hn = go * tc;
      c = cn; h = hn;

      // broadcast h: every lane writes its unit (dup halves, same value)
      hrow[kidx] = hn;
#pragma unroll
      for (int q = 0; q < 8; ++q)
        h4[q] = reinterpret_cast<const float4*>(hrow)[q];
    }
  };

  for (int it = 0; it < T_N / 4; ++it) {
    const int tbase = it * 4;
    // token group for tbase+8 (becomes "next" at end of this iteration)
    int4 tv = *reinterpret_cast<const int4*>(&tokl[wrow][tbase + 8]);

    step(tg0, tg2, p0);   // t = tbase+0, prefetch tbase+2
    step(tg1, tg3, p1);   // t = tbase+1, prefetch tbase+3
    step(tg2, tn0, p0);   // t = tbase+2, prefetch tbase+4
    step(tg3, tn1, p1);   // t = tbase+3, prefetch tbase+5

    tg0 = tn0; tg1 = tn1; tg2 = tn2; tg3 = tn3;
    tn0 = __builtin_amdgcn_readfirstlane(tv.x);
    tn1 = __builtin_amdgcn_readfirstlane(tv.y);
    tn2 = __builtin_amdgcn_readfirstlane(tv.z);
    tn3 = __builtin_amdgcn_readfirstlane(tv.w);
  }

  if (lane < 32) out[(size_t)row * HID_N + lane] = h;
}

// ---------------------------------------------------------------------------
// Fallback (no workspace for the proj table): round-1 proven kernel, inline
// x_proj. 2 rows/wave.
// ---------------------------------------------------------------------------
__device__ __forceinline__ float sigm_fb(float x) {
  return frcp(1.0f + exp2f(x * -1.4426950408889634f));
}
__device__ __forceinline__ float tanh_fb(float x) {
  float e = exp2f(x * 2.8853900817779268f);
  return fmaf(-2.0f, frcp(e + 1.0f), 1.0f);
}

__global__ __launch_bounds__(256, 2)
void lstm_scan_fallback(const int*   __restrict__ tokens,
                        const float* __restrict__ rec_kernel,
                        const float* __restrict__ emb,
                        const float* __restrict__ W,
                        const float* __restrict__ bias,
                        float*       __restrict__ out) {
  __shared__ int   tokl[8][T_N];
  __shared__ float hbuf[8][HID_N];

  const int tid  = threadIdx.x;
  const int wv   = tid >> 6;
  const int lane = tid & 63;
  const int half = lane >> 5;
  const int j    = lane & 31;
  const int wrow = wv * 2 + half;
  const int row  = blockIdx.x * 8 + wrow;

  {
    const int4* src = reinterpret_cast<const int4*>(tokens + (size_t)blockIdx.x * 8 * T_N);
    int4* dst = reinterpret_cast<int4*>(&tokl[0][0]);
    for (int i = tid; i < 8 * T_N / 4; i += 256) dst[i] = src[i];
  }

  float wr[HID_N][4];
#pragma unroll
  for (int k = 0; k < HID_N; ++k)
#pragma unroll
    for (int g = 0; g < 4; ++g) wr[k][g] = rec_kernel[k * 128 + g * 32 + j];

  float wk[EMB_N][4];
  float bb[4];
#pragma unroll
  for (int e = 0; e < EMB_N; ++e)
#pragma unroll
    for (int g = 0; g < 4; ++g) wk[e][g] = W[e * 128 + g * 32 + j];
#pragma unroll
  for (int g = 0; g < 4; ++g) bb[g] = bias[g * 32 + j];
  __syncthreads();

  float c = 0.0f, h = 0.0f;
  float4 h4[8];
#pragma unroll
  for (int q = 0; q < 8; ++q) h4[q] = make_float4(0.f, 0.f, 0.f, 0.f);

  for (int t = 0; t < T_N; ++t) {
    const int tokc = tokl[wrow][t];
    const float4* ev = reinterpret_cast<const float4*>(emb + (size_t)tokc * EMB_N);
    float4 e0 = ev[0], e1 = ev[1], e2 = ev[2], e3 = ev[3];
    const float em[16] = {e0.x,e0.y,e0.z,e0.w, e1.x,e1.y,e1.z,e1.w,
                          e2.x,e2.y,e2.z,e2.w, e3.x,e3.y,e3.z,e3.w};
    float a0 = bb[0], a1 = bb[1], a2 = bb[2], a3 = bb[3];
#pragma unroll
    for (int e = 0; e < EMB_N; ++e) {
      float x = em[e];
      a0 = fmaf(x, wk[e][0], a0); a1 = fmaf(x, wk[e][1], a1);
      a2 = fmaf(x, wk[e][2], a2); a3 = fmaf(x, wk[e][3], a3);
    }
#pragma unroll
    for (int q = 0; q < 8; ++q) {
      float hx = h4[q].x, hy = h4[q].y, hz = h4[q].z, hw = h4[q].w;
      a0 = fmaf(hx, wr[4*q+0][0], a0); a1 = fmaf(hx, wr[4*q+0][1], a1);
      a2 = fmaf(hx, wr[4*q+0][2], a2); a3 = fmaf(hx, wr[4*q+0][3], a3);
      a0 = fmaf(hy, wr[4*q+1][0], a0); a1 = fmaf(hy, wr[4*q+1][1], a1);
      a2 = fmaf(hy, wr[4*q+1][2], a2); a3 = fmaf(hy, wr[4*q+1][3], a3);
      a0 = fmaf(hz, wr[4*q+2][0], a0); a1 = fmaf(hz, wr[4*q+2][1], a1);
      a2 = fmaf(hz, wr[4*q+2][2], a2); a3 = fmaf(hz, wr[4*q+2][3], a3);
      a0 = fmaf(hw, wr[4*q+3][0], a0); a1 = fmaf(hw, wr[4*q+3][1], a1);
      a2 = fmaf(hw, wr[4*q+3][2], a2); a3 = fmaf(hw, wr[4*q+3][3], a3);
    }
    float ig = sigm_fb(a0), fg = sigm_fb(a1), gg = tanh_fb(a2), og = sigm_fb(a3);
    float cn = fmaf(fg, c, ig * gg);
    float hn = og * tanh_fb(cn);
    if (tokc != 0) { h = hn; c = cn; }
    hbuf[wrow][j] = h;
    asm volatile("" ::: "memory");
#pragma unroll
    for (int q = 0; q < 8; ++q)
      h4[q] = reinterpret_cast<const float4*>(&hbuf[wrow][0])[q];
    asm volatile("" ::: "memory");
  }
  out[(size_t)row * HID_N + j] = h;
}

extern "C" void kernel_launch(void* const* d_in, const int* in_sizes, int n_in,
                              void* d_out, int out_size, void* d_ws, size_t ws_size,
                              hipStream_t stream) {
  const int*   tokens = (const int*)  d_in[0];
  const float* emb    = (const float*)d_in[1];
  const float* W      = (const float*)d_in[2];
  const float* rec    = (const float*)d_in[3];
  const float* bias   = (const float*)d_in[4];
  float* out = (float*)d_out;

  const size_t need = (size_t)VOCAB_N * 64 * sizeof(float2);  // 25.6 MB
  if (ws_size >= need) {
    float2* proj2 = (float2*)d_ws;
    build_proj2_kernel<<<(VOCAB_N * 64) / 256 + 1, 256, 0, stream>>>(emb, W, bias, proj2);
    lstm_scan2_kernel<<<B_N / 4, 256, 0, stream>>>(tokens, rec, proj2, out);
  } else {
    lstm_scan_fallback<<<B_N / 8, 256, 0, stream>>>(tokens, rec, emb, W, bias, out);
  }
}